// Round 1
// baseline (3305.145 us; speedup 1.0000x reference)
//
#include <hip/hip_runtime.h>

#define NN 100000
#define NE 640000

// ---------------- helpers ----------------

__global__ void k_zero(float* __restrict__ p, int n) {
    int i = blockIdx.x * blockDim.x + threadIdx.x;
    if (i < n) p[i] = 0.f;
}

__global__ void k_deg(const int* __restrict__ dst, const float* __restrict__ ew,
                      float* __restrict__ deg, int E) {
    int e = blockIdx.x * blockDim.x + threadIdx.x;
    if (e < E) atomicAdd(&deg[dst[e]], ew[e]);
}

__global__ void k_dinv(float* __restrict__ deg, int n) {
    int i = blockIdx.x * blockDim.x + threadIdx.x;
    if (i < n) {
        float d = deg[i];
        deg[i] = (d > 0.f) ? rsqrtf(d) : 0.f;
    }
}

__global__ void k_norm(const int* __restrict__ src, const int* __restrict__ dst,
                       const float* __restrict__ ew, const float* __restrict__ dinv,
                       float* __restrict__ norm, int E) {
    int e = blockIdx.x * blockDim.x + threadIdx.x;
    if (e < E) norm[e] = dinv[src[e]] * ew[e] * dinv[dst[e]];
}

// ---------------- GEMM: H = X @ W ----------------
// blockDim = ROWS*DOUT threads; each sub-group of DOUT threads handles one row.
template <int DIN, int DOUT, int ROWS>
__global__ void k_gemm(const float* __restrict__ X, const float* __restrict__ W,
                       float* __restrict__ H, int N) {
    __shared__ float xs[ROWS][DIN];
    const int row0 = blockIdx.x * ROWS;
    const int tid = threadIdx.x;
    for (int i = tid; i < ROWS * DIN; i += ROWS * DOUT) {
        int r = i / DIN, c = i % DIN;
        int gr = row0 + r;
        xs[r][c] = (gr < N) ? X[gr * DIN + c] : 0.f;
    }
    __syncthreads();
    const int r = tid / DOUT;
    const int j = tid % DOUT;
    const int n = row0 + r;
    if (n >= N) return;
    float acc = 0.f;
#pragma unroll
    for (int k = 0; k < DIN; ++k) acc += xs[r][k] * W[k * DOUT + j];
    H[n * DOUT + j] = acc;
}

// ---------------- init out region with bias ----------------
template <int D>
__global__ void k_init_bias(float* __restrict__ out, const float* __restrict__ b, int N) {
    int idx = blockIdx.x * blockDim.x + threadIdx.x;
    if (idx < N * D) out[idx] = b[idx & (D - 1)];
}

// ---------------- scatter: out[dst] += norm * H[src] ----------------
template <int D>
__global__ void k_scatter(const int* __restrict__ src, const int* __restrict__ dst,
                          const float* __restrict__ norm, const float* __restrict__ H,
                          float* __restrict__ out, int E) {
    const int per_edge = D / 4;
    int idx = blockIdx.x * blockDim.x + threadIdx.x;
    if (idx >= E * per_edge) return;
    int e = idx / per_edge;
    int f4 = (idx % per_edge) * 4;
    int s = src[e], d = dst[e];
    float nv = norm[e];
    const float4 hv = *reinterpret_cast<const float4*>(&H[s * D + f4]);
    float* o = &out[d * D + f4];
    atomicAdd(&o[0], nv * hv.x);
    atomicAdd(&o[1], nv * hv.y);
    atomicAdd(&o[2], nv * hv.z);
    atomicAdd(&o[3], nv * hv.w);
}

template <int D>
__global__ void k_relu(float* __restrict__ p, int n) {
    int i = blockIdx.x * blockDim.x + threadIdx.x;
    if (i < n) p[i] = fmaxf(p[i], 0.f);
}

// ---------------- launch ----------------

extern "C" void kernel_launch(void* const* d_in, const int* in_sizes, int n_in,
                              void* d_out, int out_size, void* d_ws, size_t ws_size,
                              hipStream_t stream) {
    const float* x  = (const float*)d_in[0];
    const int*   ei = (const int*)d_in[1];
    const float* ew = (const float*)d_in[2];
    const float* W1 = (const float*)d_in[3];
    const float* b1 = (const float*)d_in[4];
    const float* W2 = (const float*)d_in[5];
    const float* b2 = (const float*)d_in[6];
    const float* W3 = (const float*)d_in[7];
    const float* b3 = (const float*)d_in[8];

    const int* src = ei;        // edge_index[0]
    const int* dst = ei + NE;   // edge_index[1]

    float* ws   = (float*)d_ws;
    float* deg  = ws;                       // NN floats (becomes dinv)
    float* norm = ws + NN;                  // NE floats
    float* h    = ws + NN + NE;             // NN*128 floats (byte offset 16B-aligned)

    float* out0 = (float*)d_out;            // [NN,128]
    float* out1 = out0 + NN * 128;          // [NN,128]
    float* out2 = out1 + NN * 128;          // [NN,64]

    const int B = 256;

    // degree -> dinv -> norm (shared across layers)
    k_zero<<<(NN + B - 1) / B, B, 0, stream>>>(deg, NN);
    k_deg<<<(NE + B - 1) / B, B, 0, stream>>>(dst, ew, deg, NE);
    k_dinv<<<(NN + B - 1) / B, B, 0, stream>>>(deg, NN);
    k_norm<<<(NE + B - 1) / B, B, 0, stream>>>(src, dst, ew, deg, norm, NE);

    // ----- layer 1: x[NN,128] @ W1 -> h; scatter -> out0; relu -----
    k_gemm<128, 128, 2><<<(NN + 1) / 2, 256, 0, stream>>>(x, W1, h, NN);
    k_init_bias<128><<<(NN * 128 + B - 1) / B, B, 0, stream>>>(out0, b1, NN);
    k_scatter<128><<<(NE * 32 + B - 1) / B, B, 0, stream>>>(src, dst, norm, h, out0, NE);
    k_relu<128><<<(NN * 128 + B - 1) / B, B, 0, stream>>>(out0, NN * 128);

    // ----- layer 2: out0 @ W2 -> h; scatter -> out1; relu -----
    k_gemm<128, 128, 2><<<(NN + 1) / 2, 256, 0, stream>>>(out0, W2, h, NN);
    k_init_bias<128><<<(NN * 128 + B - 1) / B, B, 0, stream>>>(out1, b2, NN);
    k_scatter<128><<<(NE * 32 + B - 1) / B, B, 0, stream>>>(src, dst, norm, h, out1, NE);
    k_relu<128><<<(NN * 128 + B - 1) / B, B, 0, stream>>>(out1, NN * 128);

    // ----- layer 3: out1 @ W3 -> h; scatter -> out2 (no relu) -----
    k_gemm<128, 64, 4><<<(NN + 3) / 4, 256, 0, stream>>>(out1, W3, h, NN);
    k_init_bias<64><<<(NN * 64 + B - 1) / B, B, 0, stream>>>(out2, b3, NN);
    k_scatter<64><<<(NE * 16 + B - 1) / B, B, 0, stream>>>(src, dst, norm, h, out2, NE);
}

// Round 2
// 800.470 us; speedup vs baseline: 4.1290x; 4.1290x over previous
//
#include <hip/hip_runtime.h>

#define NN 100000
#define NE 640000

// ---------------- degree + histogram ----------------

__global__ void k_deg_hist(const int* __restrict__ dst, const float* __restrict__ ew,
                           float* __restrict__ deg, int* __restrict__ cnt, int E) {
    int e = blockIdx.x * blockDim.x + threadIdx.x;
    if (e < E) {
        int d = dst[e];
        atomicAdd(&deg[d], ew[e]);
        atomicAdd(&cnt[d], 1);
    }
}

__global__ void k_dinv(float* __restrict__ deg, int n) {
    int i = blockIdx.x * blockDim.x + threadIdx.x;
    if (i < n) {
        float d = deg[i];
        deg[i] = (d > 0.f) ? rsqrtf(d) : 0.f;
    }
}

// ---------------- exclusive scan over cnt[0..n) -> rp ----------------
// scan1: 1024 elems/block (256 thr x 4), block sums out
__global__ void k_scan1(const int* __restrict__ cnt, int* __restrict__ rp,
                        int* __restrict__ bsum, int n) {
    __shared__ int tsum[256];
    const int base = blockIdx.x * 1024;
    const int t = threadIdx.x;
    int v[4], s = 0;
#pragma unroll
    for (int j = 0; j < 4; ++j) {
        int idx = base + t * 4 + j;
        v[j] = (idx < n) ? cnt[idx] : 0;
        s += v[j];
    }
    tsum[t] = s;
    __syncthreads();
    for (int off = 1; off < 256; off <<= 1) {
        int x = (t >= off) ? tsum[t - off] : 0;
        __syncthreads();
        tsum[t] += x;
        __syncthreads();
    }
    int excl = (t > 0) ? tsum[t - 1] : 0;
#pragma unroll
    for (int j = 0; j < 4; ++j) {
        int idx = base + t * 4 + j;
        if (idx < n) rp[idx] = excl;
        excl += v[j];
    }
    if (t == 255) bsum[blockIdx.x] = tsum[255];
}

// scan2: single block, exclusive-scan bsum in place (nb <= 256)
__global__ void k_scan2(int* __restrict__ bsum, int nb) {
    __shared__ int sh[256];
    int t = threadIdx.x;
    sh[t] = (t < nb) ? bsum[t] : 0;
    __syncthreads();
    for (int off = 1; off < 256; off <<= 1) {
        int x = (t >= off) ? sh[t - off] : 0;
        __syncthreads();
        sh[t] += x;
        __syncthreads();
    }
    if (t < nb) bsum[t] = (t > 0) ? sh[t - 1] : 0;
}

// scan3: add block offsets; write rp[n] = total edges
__global__ void k_scan3(int* __restrict__ rp, const int* __restrict__ bsum, int n) {
    int i = blockIdx.x * blockDim.x + threadIdx.x;
    if (i < n) rp[i] += bsum[i >> 10];
    if (i == 0) rp[n] = NE;
}

// ---------------- fill CSR buckets ----------------
__global__ void k_fill(const int* __restrict__ src, const int* __restrict__ dst,
                       const float* __restrict__ ew, const float* __restrict__ dinv,
                       int* __restrict__ cursor, int* __restrict__ esrc,
                       float* __restrict__ enorm, int E) {
    int e = blockIdx.x * blockDim.x + threadIdx.x;
    if (e < E) {
        int s = src[e], d = dst[e];
        int pos = atomicAdd(&cursor[d], 1);
        esrc[pos] = s;
        enorm[pos] = dinv[s] * ew[e] * dinv[d];
    }
}

// ---------------- GEMM: H = X @ W ----------------
template <int DIN, int DOUT, int ROWS>
__global__ void k_gemm(const float* __restrict__ X, const float* __restrict__ W,
                       float* __restrict__ H, int N) {
    __shared__ float xs[ROWS][DIN];
    const int row0 = blockIdx.x * ROWS;
    const int tid = threadIdx.x;
    for (int i = tid; i < ROWS * DIN; i += ROWS * DOUT) {
        int r = i / DIN, c = i % DIN;
        int gr = row0 + r;
        xs[r][c] = (gr < N) ? X[gr * DIN + c] : 0.f;
    }
    __syncthreads();
    const int r = tid / DOUT;
    const int j = tid % DOUT;
    const int n = row0 + r;
    if (n >= N) return;
    float acc = 0.f;
#pragma unroll
    for (int k = 0; k < DIN; ++k) acc = fmaf(xs[r][k], W[k * DOUT + j], acc);
    H[n * DOUT + j] = acc;
}

// ---------------- aggregate: out[n] = relu?(sum_e norm*H[src] + b) ----------------
// One wave per destination node; lane covers feature dims.
template <int D, int WAVES, int RELU>
__global__ void k_agg(const int* __restrict__ rp, const int* __restrict__ esrc,
                      const float* __restrict__ enorm, const float* __restrict__ H,
                      const float* __restrict__ b, float* __restrict__ out, int N) {
    const int wave = threadIdx.x >> 6;
    const int lane = threadIdx.x & 63;
    const int n = blockIdx.x * WAVES + wave;
    if (n >= N) return;
    const int e0 = rp[n], e1 = rp[n + 1];
    if constexpr (D == 128) {
        const float2* __restrict__ H2 = (const float2*)H;
        float2 acc = ((const float2*)b)[lane];
        for (int e = e0; e < e1; ++e) {
            int s = esrc[e];
            float w = enorm[e];
            float2 v = H2[s * 64 + lane];
            acc.x = fmaf(w, v.x, acc.x);
            acc.y = fmaf(w, v.y, acc.y);
        }
        if (RELU) { acc.x = fmaxf(acc.x, 0.f); acc.y = fmaxf(acc.y, 0.f); }
        ((float2*)out)[(size_t)n * 64 + lane] = acc;
    } else {  // D == 64
        float acc = b[lane];
        for (int e = e0; e < e1; ++e) {
            int s = esrc[e];
            float w = enorm[e];
            acc = fmaf(w, H[s * 64 + lane], acc);
        }
        if (RELU) acc = fmaxf(acc, 0.f);
        out[(size_t)n * 64 + lane] = acc;
    }
}

// ---------------- launch ----------------

extern "C" void kernel_launch(void* const* d_in, const int* in_sizes, int n_in,
                              void* d_out, int out_size, void* d_ws, size_t ws_size,
                              hipStream_t stream) {
    const float* x  = (const float*)d_in[0];
    const int*   ei = (const int*)d_in[1];
    const float* ew = (const float*)d_in[2];
    const float* W1 = (const float*)d_in[3];
    const float* b1 = (const float*)d_in[4];
    const float* W2 = (const float*)d_in[5];
    const float* b2 = (const float*)d_in[6];
    const float* W3 = (const float*)d_in[7];
    const float* b3 = (const float*)d_in[8];

    const int* src = ei;        // edge_index[0]
    const int* dst = ei + NE;   // edge_index[1]

    // ws layout
    float* ws    = (float*)d_ws;
    float* deg   = ws;                        // NN f  (becomes dinv)
    int*   cnt   = (int*)(ws + NN);           // NN i  (histogram, then cursor)
    int*   rp    = (int*)(ws + 2 * NN);       // NN+1 i
    int*   bsum  = (int*)(ws + 3 * NN + 64);  // 128 i
    int*   esrc  = (int*)(ws + 3 * NN + 256); // NE i
    float* enorm = ws + 3 * NN + 256 + NE;    // NE f
    float* h     = ws + 3 * NN + 256 + 2 * NE;// NN*128 f

    float* out0 = (float*)d_out;              // [NN,128]
    float* out1 = out0 + NN * 128;            // [NN,128]
    float* out2 = out1 + NN * 128;            // [NN,64]

    const int B = 256;
    const int NB_SCAN = (NN + 1023) / 1024;   // 98

    hipMemsetAsync(deg, 0, NN * sizeof(float), stream);
    hipMemsetAsync(cnt, 0, NN * sizeof(int), stream);

    k_deg_hist<<<(NE + B - 1) / B, B, 0, stream>>>(dst, ew, deg, cnt, NE);
    k_dinv<<<(NN + B - 1) / B, B, 0, stream>>>(deg, NN);
    k_scan1<<<NB_SCAN, 256, 0, stream>>>(cnt, rp, bsum, NN);
    k_scan2<<<1, 256, 0, stream>>>(bsum, NB_SCAN);
    k_scan3<<<(NN + B - 1) / B, B, 0, stream>>>(rp, bsum, NN);
    hipMemcpyAsync(cnt, rp, NN * sizeof(int), hipMemcpyDeviceToDevice, stream);
    k_fill<<<(NE + B - 1) / B, B, 0, stream>>>(src, dst, ew, deg, cnt, esrc, enorm, NE);

    // ----- layer 1 -----
    k_gemm<128, 128, 2><<<(NN + 1) / 2, 256, 0, stream>>>(x, W1, h, NN);
    k_agg<128, 4, 1><<<(NN + 3) / 4, 256, 0, stream>>>(rp, esrc, enorm, h, b1, out0, NN);

    // ----- layer 2 -----
    k_gemm<128, 128, 2><<<(NN + 1) / 2, 256, 0, stream>>>(out0, W2, h, NN);
    k_agg<128, 4, 1><<<(NN + 3) / 4, 256, 0, stream>>>(rp, esrc, enorm, h, b2, out1, NN);

    // ----- layer 3 -----
    k_gemm<128, 64, 4><<<(NN + 3) / 4, 256, 0, stream>>>(out1, W3, h, NN);
    k_agg<64, 4, 0><<<(NN + 3) / 4, 256, 0, stream>>>(rp, esrc, enorm, h, b3, out2, NN);
}

// Round 3
// 485.805 us; speedup vs baseline: 6.8034x; 1.6477x over previous
//
#include <hip/hip_runtime.h>

#define NN 100000
#define NE 640000

// ---------------- degree + histogram ----------------

__global__ void k_deg_hist(const int* __restrict__ dst, const float* __restrict__ ew,
                           float* __restrict__ deg, int* __restrict__ cnt, int E) {
    int e = blockIdx.x * blockDim.x + threadIdx.x;
    if (e < E) {
        int d = dst[e];
        atomicAdd(&deg[d], ew[e]);
        atomicAdd(&cnt[d], 1);
    }
}

__global__ void k_dinv(float* __restrict__ deg, int n) {
    int i = blockIdx.x * blockDim.x + threadIdx.x;
    if (i < n) {
        float d = deg[i];
        deg[i] = (d > 0.f) ? rsqrtf(d) : 0.f;
    }
}

// ---------------- exclusive scan over cnt[0..n) -> rp ----------------

__global__ void k_scan1(const int* __restrict__ cnt, int* __restrict__ rp,
                        int* __restrict__ bsum, int n) {
    __shared__ int tsum[256];
    const int base = blockIdx.x * 1024;
    const int t = threadIdx.x;
    int v[4], s = 0;
#pragma unroll
    for (int j = 0; j < 4; ++j) {
        int idx = base + t * 4 + j;
        v[j] = (idx < n) ? cnt[idx] : 0;
        s += v[j];
    }
    tsum[t] = s;
    __syncthreads();
    for (int off = 1; off < 256; off <<= 1) {
        int x = (t >= off) ? tsum[t - off] : 0;
        __syncthreads();
        tsum[t] += x;
        __syncthreads();
    }
    int excl = (t > 0) ? tsum[t - 1] : 0;
#pragma unroll
    for (int j = 0; j < 4; ++j) {
        int idx = base + t * 4 + j;
        if (idx < n) rp[idx] = excl;
        excl += v[j];
    }
    if (t == 255) bsum[blockIdx.x] = tsum[255];
}

__global__ void k_scan2(int* __restrict__ bsum, int nb) {
    __shared__ int sh[256];
    int t = threadIdx.x;
    sh[t] = (t < nb) ? bsum[t] : 0;
    __syncthreads();
    for (int off = 1; off < 256; off <<= 1) {
        int x = (t >= off) ? sh[t - off] : 0;
        __syncthreads();
        sh[t] += x;
        __syncthreads();
    }
    if (t < nb) bsum[t] = (t > 0) ? sh[t - 1] : 0;
}

__global__ void k_scan3(int* __restrict__ rp, const int* __restrict__ bsum, int n) {
    int i = blockIdx.x * blockDim.x + threadIdx.x;
    if (i < n) rp[i] += bsum[i >> 10];
    if (i == 0) rp[n] = NE;
}

// ---------------- fill CSR buckets ----------------
__global__ void k_fill(const int* __restrict__ src, const int* __restrict__ dst,
                       const float* __restrict__ ew, const float* __restrict__ dinv,
                       int* __restrict__ cursor, int* __restrict__ esrc,
                       float* __restrict__ enorm, int E) {
    int e = blockIdx.x * blockDim.x + threadIdx.x;
    if (e < E) {
        int s = src[e], d = dst[e];
        int pos = atomicAdd(&cursor[d], 1);
        esrc[pos] = s;
        enorm[pos] = dinv[s] * ew[e] * dinv[d];
    }
}

// ---------------- register-tiled GEMM: H = X @ W  (X: [N,128], W: [128,BN]) ----------------
template <int BM, int BN, int BK, int TM, int TN>
__global__ __launch_bounds__(256) void k_gemm_tiled(const float* __restrict__ X,
                                                    const float* __restrict__ W,
                                                    float* __restrict__ H, int N) {
    constexpr int THREADS = (BM / TM) * (BN / TN);
    static_assert(THREADS == 256, "block must be 256 threads");
    __shared__ float xs[BK][BM];   // X tile, transposed
    __shared__ float ws[BK][BN];   // W tile
    const int row0 = blockIdx.x * BM;
    const int tid = threadIdx.x;
    constexpr int NTX = BN / TN;
    const int tx = tid % NTX;
    const int ty = tid / NTX;
    const int c0 = tx * TN;
    const int r0 = ty * TM;

    float acc[TM][TN] = {};

    for (int k0 = 0; k0 < 128; k0 += BK) {
        // stage X tile (BM x BK) -> xs[kk][r] (transpose via scalar LDS writes)
        constexpr int XQ = BM * BK / 4;
        constexpr int QPR = BK / 4;
        for (int i = tid; i < XQ; i += THREADS) {
            int r = i / QPR, q = i % QPR;
            int gr = row0 + r;
            float4 v = make_float4(0.f, 0.f, 0.f, 0.f);
            if (gr < N) v = *reinterpret_cast<const float4*>(&X[(size_t)gr * 128 + k0 + q * 4]);
            xs[q * 4 + 0][r] = v.x;
            xs[q * 4 + 1][r] = v.y;
            xs[q * 4 + 2][r] = v.z;
            xs[q * 4 + 3][r] = v.w;
        }
        // stage W tile (BK x BN), row-major, vector copy
        constexpr int WQ = BK * BN / 4;
        constexpr int WQPR = BN / 4;
        for (int i = tid; i < WQ; i += THREADS) {
            int kk = i / WQPR, q = i % WQPR;
            *reinterpret_cast<float4*>(&ws[kk][q * 4]) =
                *reinterpret_cast<const float4*>(&W[(size_t)(k0 + kk) * BN + q * 4]);
        }
        __syncthreads();
#pragma unroll 4
        for (int kk = 0; kk < BK; ++kk) {
            float xr[TM], wr[TN];
#pragma unroll
            for (int i = 0; i < TM; ++i) xr[i] = xs[kk][r0 + i];
#pragma unroll
            for (int j = 0; j < TN; ++j) wr[j] = ws[kk][c0 + j];
#pragma unroll
            for (int i = 0; i < TM; ++i)
#pragma unroll
                for (int j = 0; j < TN; ++j)
                    acc[i][j] = fmaf(xr[i], wr[j], acc[i][j]);
        }
        __syncthreads();
    }
#pragma unroll
    for (int i = 0; i < TM; ++i) {
        int gr = row0 + r0 + i;
        if (gr < N) {
            float4* p = reinterpret_cast<float4*>(&H[(size_t)gr * BN + c0]);
            p[0] = make_float4(acc[i][0], acc[i][1], acc[i][2], acc[i][3]);
            p[1] = make_float4(acc[i][4], acc[i][5], acc[i][6], acc[i][7]);
        }
    }
}

// ---------------- aggregate: out[n] = relu?(sum_e norm*H[src] + b) ----------------
template <int D, int WAVES, int RELU>
__global__ void k_agg(const int* __restrict__ rp, const int* __restrict__ esrc,
                      const float* __restrict__ enorm, const float* __restrict__ H,
                      const float* __restrict__ b, float* __restrict__ out, int N) {
    const int wave = threadIdx.x >> 6;
    const int lane = threadIdx.x & 63;
    const int n = blockIdx.x * WAVES + wave;
    if (n >= N) return;
    const int e0 = rp[n], e1 = rp[n + 1];
    if constexpr (D == 128) {
        const float2* __restrict__ H2 = (const float2*)H;
        float2 acc = ((const float2*)b)[lane];
        for (int e = e0; e < e1; ++e) {
            int s = esrc[e];
            float w = enorm[e];
            float2 v = H2[s * 64 + lane];
            acc.x = fmaf(w, v.x, acc.x);
            acc.y = fmaf(w, v.y, acc.y);
        }
        if (RELU) { acc.x = fmaxf(acc.x, 0.f); acc.y = fmaxf(acc.y, 0.f); }
        ((float2*)out)[(size_t)n * 64 + lane] = acc;
    } else {  // D == 64
        float acc = b[lane];
        for (int e = e0; e < e1; ++e) {
            int s = esrc[e];
            float w = enorm[e];
            acc = fmaf(w, H[s * 64 + lane], acc);
        }
        if (RELU) acc = fmaxf(acc, 0.f);
        out[(size_t)n * 64 + lane] = acc;
    }
}

// ---------------- launch ----------------

extern "C" void kernel_launch(void* const* d_in, const int* in_sizes, int n_in,
                              void* d_out, int out_size, void* d_ws, size_t ws_size,
                              hipStream_t stream) {
    const float* x  = (const float*)d_in[0];
    const int*   ei = (const int*)d_in[1];
    const float* ew = (const float*)d_in[2];
    const float* W1 = (const float*)d_in[3];
    const float* b1 = (const float*)d_in[4];
    const float* W2 = (const float*)d_in[5];
    const float* b2 = (const float*)d_in[6];
    const float* W3 = (const float*)d_in[7];
    const float* b3 = (const float*)d_in[8];

    const int* src = ei;        // edge_index[0]
    const int* dst = ei + NE;   // edge_index[1]

    // ws layout
    float* ws    = (float*)d_ws;
    float* deg   = ws;                        // NN f  (becomes dinv)
    int*   cnt   = (int*)(ws + NN);           // NN i  (histogram, then cursor)
    int*   rp    = (int*)(ws + 2 * NN);       // NN+1 i
    int*   bsum  = (int*)(ws + 3 * NN + 64);  // 128 i
    int*   esrc  = (int*)(ws + 3 * NN + 256); // NE i
    float* enorm = ws + 3 * NN + 256 + NE;    // NE f
    float* h     = ws + 3 * NN + 256 + 2 * NE;// NN*128 f

    float* out0 = (float*)d_out;              // [NN,128]
    float* out1 = out0 + NN * 128;            // [NN,128]
    float* out2 = out1 + NN * 128;            // [NN,64]

    const int B = 256;
    const int NB_SCAN = (NN + 1023) / 1024;   // 98

    hipMemsetAsync(deg, 0, NN * sizeof(float), stream);
    hipMemsetAsync(cnt, 0, NN * sizeof(int), stream);

    k_deg_hist<<<(NE + B - 1) / B, B, 0, stream>>>(dst, ew, deg, cnt, NE);
    k_dinv<<<(NN + B - 1) / B, B, 0, stream>>>(deg, NN);
    k_scan1<<<NB_SCAN, 256, 0, stream>>>(cnt, rp, bsum, NN);
    k_scan2<<<1, 256, 0, stream>>>(bsum, NB_SCAN);
    k_scan3<<<(NN + B - 1) / B, B, 0, stream>>>(rp, bsum, NN);
    hipMemcpyAsync(cnt, rp, NN * sizeof(int), hipMemcpyDeviceToDevice, stream);
    k_fill<<<(NE + B - 1) / B, B, 0, stream>>>(src, dst, ew, deg, cnt, esrc, enorm, NE);

    // ----- layer 1 -----
    k_gemm_tiled<128, 128, 16, 8, 8><<<(NN + 127) / 128, 256, 0, stream>>>(x, W1, h, NN);
    k_agg<128, 4, 1><<<(NN + 3) / 4, 256, 0, stream>>>(rp, esrc, enorm, h, b1, out0, NN);

    // ----- layer 2 -----
    k_gemm_tiled<128, 128, 16, 8, 8><<<(NN + 127) / 128, 256, 0, stream>>>(out0, W2, h, NN);
    k_agg<128, 4, 1><<<(NN + 3) / 4, 256, 0, stream>>>(rp, esrc, enorm, h, b2, out1, NN);

    // ----- layer 3 -----
    k_gemm_tiled<256, 64, 16, 8, 8><<<(NN + 255) / 256, 256, 0, stream>>>(out1, W3, h, NN);
    k_agg<64, 4, 0><<<(NN + 3) / 4, 256, 0, stream>>>(rp, esrc, enorm, h, b3, out2, NN);
}

// Round 4
// 413.709 us; speedup vs baseline: 7.9891x; 1.1743x over previous
//
#include <hip/hip_runtime.h>

#define NN 100000
#define NE 640000

typedef unsigned int uint32;
typedef unsigned short ushort16;

static __device__ __forceinline__ ushort f2bf(float f) {
    uint32 u = __float_as_uint(f);
    u = (u + 0x7fffu + ((u >> 16) & 1u)) >> 16;
    return (ushort)u;
}
static __device__ __forceinline__ float bf2f(uint32 bits16) {
    return __uint_as_float(bits16 << 16);
}

// ---------------- degree + histogram ----------------

__global__ void k_deg_hist(const int* __restrict__ dst, const float* __restrict__ ew,
                           float* __restrict__ deg, int* __restrict__ cnt, int E) {
    int e = blockIdx.x * blockDim.x + threadIdx.x;
    if (e < E) {
        int d = dst[e];
        atomicAdd(&deg[d], ew[e]);
        atomicAdd(&cnt[d], 1);
    }
}

__global__ void k_dinv(float* __restrict__ deg, int n) {
    int i = blockIdx.x * blockDim.x + threadIdx.x;
    if (i < n) {
        float d = deg[i];
        deg[i] = (d > 0.f) ? rsqrtf(d) : 0.f;
    }
}

// ---------------- exclusive scan over cnt[0..n) -> rp ----------------

__global__ void k_scan1(const int* __restrict__ cnt, int* __restrict__ rp,
                        int* __restrict__ bsum, int n) {
    __shared__ int tsum[256];
    const int base = blockIdx.x * 1024;
    const int t = threadIdx.x;
    int v[4], s = 0;
#pragma unroll
    for (int j = 0; j < 4; ++j) {
        int idx = base + t * 4 + j;
        v[j] = (idx < n) ? cnt[idx] : 0;
        s += v[j];
    }
    tsum[t] = s;
    __syncthreads();
    for (int off = 1; off < 256; off <<= 1) {
        int x = (t >= off) ? tsum[t - off] : 0;
        __syncthreads();
        tsum[t] += x;
        __syncthreads();
    }
    int excl = (t > 0) ? tsum[t - 1] : 0;
#pragma unroll
    for (int j = 0; j < 4; ++j) {
        int idx = base + t * 4 + j;
        if (idx < n) rp[idx] = excl;
        excl += v[j];
    }
    if (t == 255) bsum[blockIdx.x] = tsum[255];
}

__global__ void k_scan2(int* __restrict__ bsum, int nb) {
    __shared__ int sh[256];
    int t = threadIdx.x;
    sh[t] = (t < nb) ? bsum[t] : 0;
    __syncthreads();
    for (int off = 1; off < 256; off <<= 1) {
        int x = (t >= off) ? sh[t - off] : 0;
        __syncthreads();
        sh[t] += x;
        __syncthreads();
    }
    if (t < nb) bsum[t] = (t > 0) ? sh[t - 1] : 0;
}

__global__ void k_scan3(int* __restrict__ rp, const int* __restrict__ bsum, int n) {
    int i = blockIdx.x * blockDim.x + threadIdx.x;
    if (i < n) rp[i] += bsum[i >> 10];
    if (i == 0) rp[n] = NE;
}

// ---------------- fill CSR buckets: ep[pos] = (src, norm) ----------------
__global__ void k_fill(const int* __restrict__ src, const int* __restrict__ dst,
                       const float* __restrict__ ew, const float* __restrict__ dinv,
                       int* __restrict__ cursor, uint2* __restrict__ ep, int E) {
    int e = blockIdx.x * blockDim.x + threadIdx.x;
    if (e < E) {
        int s = src[e], d = dst[e];
        int pos = atomicAdd(&cursor[d], 1);
        float nv = dinv[s] * ew[e] * dinv[d];
        ep[pos] = make_uint2((uint32)s, __float_as_uint(nv));
    }
}

// ---------------- register-tiled GEMM: H(bf16) = X(f32) @ W(f32) ----------------
template <int BM, int BN, int BK, int TM, int TN>
__global__ __launch_bounds__(256) void k_gemm_tiled(const float* __restrict__ X,
                                                    const float* __restrict__ W,
                                                    ushort* __restrict__ H, int N) {
    constexpr int THREADS = (BM / TM) * (BN / TN);
    static_assert(THREADS == 256, "block must be 256 threads");
    __shared__ float xs[BK][BM];
    __shared__ float ws[BK][BN];
    const int row0 = blockIdx.x * BM;
    const int tid = threadIdx.x;
    constexpr int NTX = BN / TN;
    const int tx = tid % NTX;
    const int ty = tid / NTX;
    const int c0 = tx * TN;
    const int r0 = ty * TM;

    float acc[TM][TN] = {};

    for (int k0 = 0; k0 < 128; k0 += BK) {
        constexpr int XQ = BM * BK / 4;
        constexpr int QPR = BK / 4;
        for (int i = tid; i < XQ; i += THREADS) {
            int r = i / QPR, q = i % QPR;
            int gr = row0 + r;
            float4 v = make_float4(0.f, 0.f, 0.f, 0.f);
            if (gr < N) v = *reinterpret_cast<const float4*>(&X[(size_t)gr * 128 + k0 + q * 4]);
            xs[q * 4 + 0][r] = v.x;
            xs[q * 4 + 1][r] = v.y;
            xs[q * 4 + 2][r] = v.z;
            xs[q * 4 + 3][r] = v.w;
        }
        constexpr int WQ = BK * BN / 4;
        constexpr int WQPR = BN / 4;
        for (int i = tid; i < WQ; i += THREADS) {
            int kk = i / WQPR, q = i % WQPR;
            *reinterpret_cast<float4*>(&ws[kk][q * 4]) =
                *reinterpret_cast<const float4*>(&W[(size_t)(k0 + kk) * BN + q * 4]);
        }
        __syncthreads();
#pragma unroll 4
        for (int kk = 0; kk < BK; ++kk) {
            float xr[TM], wr[TN];
#pragma unroll
            for (int i = 0; i < TM; ++i) xr[i] = xs[kk][r0 + i];
#pragma unroll
            for (int j = 0; j < TN; ++j) wr[j] = ws[kk][c0 + j];
#pragma unroll
            for (int i = 0; i < TM; ++i)
#pragma unroll
                for (int j = 0; j < TN; ++j)
                    acc[i][j] = fmaf(xr[i], wr[j], acc[i][j]);
        }
        __syncthreads();
    }
#pragma unroll
    for (int i = 0; i < TM; ++i) {
        int gr = row0 + r0 + i;
        if (gr < N) {
            uint4 st;
            st.x = (uint32)f2bf(acc[i][0]) | ((uint32)f2bf(acc[i][1]) << 16);
            st.y = (uint32)f2bf(acc[i][2]) | ((uint32)f2bf(acc[i][3]) << 16);
            st.z = (uint32)f2bf(acc[i][4]) | ((uint32)f2bf(acc[i][5]) << 16);
            st.w = (uint32)f2bf(acc[i][6]) | ((uint32)f2bf(acc[i][7]) << 16);
            *reinterpret_cast<uint4*>(&H[(size_t)gr * BN + c0]) = st;
        }
    }
}

// ---------------- aggregate (D=128): 2-edge-parallel wave per node ----------------
// lanes 0-31: even edges, lanes 32-63: odd edges; each slot-lane covers feats 4l..4l+3.
template <int WAVES, int RELU>
__global__ void k_agg128(const int* __restrict__ rp, const uint2* __restrict__ ep,
                         const ushort* __restrict__ H, const float* __restrict__ b,
                         float* __restrict__ out, int N) {
    const int wave = threadIdx.x >> 6;
    const int lane = threadIdx.x & 63;
    const int n = blockIdx.x * WAVES + wave;
    if (n >= N) return;
    const int e0 = rp[n], e1 = rp[n + 1];
    const int slot = lane >> 5;
    const int l = lane & 31;

    float ax = 0.f, ay = 0.f, az = 0.f, aw = 0.f;
    for (int e = e0 + slot; e < e1; e += 2) {
        uint2 p = ep[e];
        int s = (int)p.x;
        float w = __uint_as_float(p.y);
        uint2 hv = *reinterpret_cast<const uint2*>(&H[(size_t)s * 128 + l * 4]);
        ax = fmaf(w, bf2f(hv.x & 0xffffu), ax);
        ay = fmaf(w, bf2f(hv.x >> 16), ay);
        az = fmaf(w, bf2f(hv.y & 0xffffu), az);
        aw = fmaf(w, bf2f(hv.y >> 16), aw);
    }
    ax += __shfl_xor(ax, 32);
    ay += __shfl_xor(ay, 32);
    az += __shfl_xor(az, 32);
    aw += __shfl_xor(aw, 32);
    if (lane < 32) {
        const float4 bb = *reinterpret_cast<const float4*>(&b[l * 4]);
        ax += bb.x; ay += bb.y; az += bb.z; aw += bb.w;
        if (RELU) {
            ax = fmaxf(ax, 0.f); ay = fmaxf(ay, 0.f);
            az = fmaxf(az, 0.f); aw = fmaxf(aw, 0.f);
        }
        *reinterpret_cast<float4*>(&out[(size_t)n * 128 + l * 4]) =
            make_float4(ax, ay, az, aw);
    }
}

// ---------------- aggregate (D=64): 2-edge-parallel wave per node ----------------
template <int WAVES, int RELU>
__global__ void k_agg64(const int* __restrict__ rp, const uint2* __restrict__ ep,
                        const ushort* __restrict__ H, const float* __restrict__ b,
                        float* __restrict__ out, int N) {
    const int wave = threadIdx.x >> 6;
    const int lane = threadIdx.x & 63;
    const int n = blockIdx.x * WAVES + wave;
    if (n >= N) return;
    const int e0 = rp[n], e1 = rp[n + 1];
    const int slot = lane >> 5;
    const int l = lane & 31;

    float ax = 0.f, ay = 0.f;
    for (int e = e0 + slot; e < e1; e += 2) {
        uint2 p = ep[e];
        int s = (int)p.x;
        float w = __uint_as_float(p.y);
        uint32 hv = *reinterpret_cast<const uint32*>(&H[(size_t)s * 64 + l * 2]);
        ax = fmaf(w, bf2f(hv & 0xffffu), ax);
        ay = fmaf(w, bf2f(hv >> 16), ay);
    }
    ax += __shfl_xor(ax, 32);
    ay += __shfl_xor(ay, 32);
    if (lane < 32) {
        const float2 bb = *reinterpret_cast<const float2*>(&b[l * 2]);
        ax += bb.x; ay += bb.y;
        if (RELU) { ax = fmaxf(ax, 0.f); ay = fmaxf(ay, 0.f); }
        *reinterpret_cast<float2*>(&out[(size_t)n * 64 + l * 2]) = make_float2(ax, ay);
    }
}

// ---------------- launch ----------------

extern "C" void kernel_launch(void* const* d_in, const int* in_sizes, int n_in,
                              void* d_out, int out_size, void* d_ws, size_t ws_size,
                              hipStream_t stream) {
    const float* x  = (const float*)d_in[0];
    const int*   ei = (const int*)d_in[1];
    const float* ew = (const float*)d_in[2];
    const float* W1 = (const float*)d_in[3];
    const float* b1 = (const float*)d_in[4];
    const float* W2 = (const float*)d_in[5];
    const float* b2 = (const float*)d_in[6];
    const float* W3 = (const float*)d_in[7];
    const float* b3 = (const float*)d_in[8];

    const int* src = ei;
    const int* dst = ei + NE;

    // ws layout
    float*  ws    = (float*)d_ws;
    float*  deg   = ws;                         // NN f (becomes dinv)
    int*    cnt   = (int*)(ws + NN);            // NN i (histogram -> cursor)
    int*    rp    = (int*)(ws + 2 * NN);        // NN+1 i
    int*    bsum  = (int*)(ws + 3 * NN + 64);   // 128 i
    uint2*  ep    = (uint2*)(ws + 3 * NN + 256);// NE uint2 (src, norm)
    ushort* h     = (ushort*)(ws + 3 * NN + 256 + 2 * NE); // NN*128 bf16

    float* out0 = (float*)d_out;                // [NN,128]
    float* out1 = out0 + NN * 128;              // [NN,128]
    float* out2 = out1 + NN * 128;              // [NN,64]

    const int B = 256;
    const int NB_SCAN = (NN + 1023) / 1024;     // 98

    hipMemsetAsync(deg, 0, NN * sizeof(float), stream);
    hipMemsetAsync(cnt, 0, NN * sizeof(int), stream);

    k_deg_hist<<<(NE + B - 1) / B, B, 0, stream>>>(dst, ew, deg, cnt, NE);
    k_dinv<<<(NN + B - 1) / B, B, 0, stream>>>(deg, NN);
    k_scan1<<<NB_SCAN, 256, 0, stream>>>(cnt, rp, bsum, NN);
    k_scan2<<<1, 256, 0, stream>>>(bsum, NB_SCAN);
    k_scan3<<<(NN + B - 1) / B, B, 0, stream>>>(rp, bsum, NN);
    hipMemcpyAsync(cnt, rp, NN * sizeof(int), hipMemcpyDeviceToDevice, stream);
    k_fill<<<(NE + B - 1) / B, B, 0, stream>>>(src, dst, ew, deg, cnt, ep, NE);

    // ----- layer 1 -----
    k_gemm_tiled<128, 128, 16, 8, 8><<<(NN + 127) / 128, 256, 0, stream>>>(x, W1, h, NN);
    k_agg128<4, 1><<<(NN + 3) / 4, 256, 0, stream>>>(rp, ep, h, b1, out0, NN);

    // ----- layer 2 -----
    k_gemm_tiled<128, 128, 16, 8, 8><<<(NN + 127) / 128, 256, 0, stream>>>(out0, W2, h, NN);
    k_agg128<4, 1><<<(NN + 3) / 4, 256, 0, stream>>>(rp, ep, h, b2, out1, NN);

    // ----- layer 3 -----
    k_gemm_tiled<256, 64, 16, 8, 8><<<(NN + 255) / 256, 256, 0, stream>>>(out1, W3, h, NN);
    k_agg64<4, 0><<<(NN + 3) / 4, 256, 0, stream>>>(rp, ep, h, b3, out2, NN);
}

// Round 5
// 287.385 us; speedup vs baseline: 11.5008x; 1.4396x over previous
//
#include <hip/hip_runtime.h>

#define NN 100000
#define NE 640000

typedef unsigned int uint32;
typedef __attribute__((ext_vector_type(8))) short short8;
typedef __attribute__((ext_vector_type(4))) float f32x4;

static __device__ __forceinline__ ushort f2bf(float f) {
    uint32 u = __float_as_uint(f);
    u = (u + 0x7fffu + ((u >> 16) & 1u)) >> 16;
    return (ushort)u;
}
static __device__ __forceinline__ float bf2f(uint32 bits16) {
    return __uint_as_float(bits16 << 16);
}

// ---------------- degree + histogram ----------------

__global__ void k_deg_hist(const int* __restrict__ dst, const float* __restrict__ ew,
                           float* __restrict__ deg, int* __restrict__ cnt, int E) {
    int e = blockIdx.x * blockDim.x + threadIdx.x;
    if (e < E) {
        int d = dst[e];
        atomicAdd(&deg[d], ew[e]);
        atomicAdd(&cnt[d], 1);
    }
}

__global__ void k_dinv(float* __restrict__ deg, int n) {
    int i = blockIdx.x * blockDim.x + threadIdx.x;
    if (i < n) {
        float d = deg[i];
        deg[i] = (d > 0.f) ? rsqrtf(d) : 0.f;
    }
}

// ---------------- exclusive scan over cnt[0..n) -> rp ----------------

__global__ void k_scan1(const int* __restrict__ cnt, int* __restrict__ rp,
                        int* __restrict__ bsum, int n) {
    __shared__ int tsum[256];
    const int base = blockIdx.x * 1024;
    const int t = threadIdx.x;
    int v[4], s = 0;
#pragma unroll
    for (int j = 0; j < 4; ++j) {
        int idx = base + t * 4 + j;
        v[j] = (idx < n) ? cnt[idx] : 0;
        s += v[j];
    }
    tsum[t] = s;
    __syncthreads();
    for (int off = 1; off < 256; off <<= 1) {
        int x = (t >= off) ? tsum[t - off] : 0;
        __syncthreads();
        tsum[t] += x;
        __syncthreads();
    }
    int excl = (t > 0) ? tsum[t - 1] : 0;
#pragma unroll
    for (int j = 0; j < 4; ++j) {
        int idx = base + t * 4 + j;
        if (idx < n) rp[idx] = excl;
        excl += v[j];
    }
    if (t == 255) bsum[blockIdx.x] = tsum[255];
}

__global__ void k_scan2(int* __restrict__ bsum, int nb) {
    __shared__ int sh[256];
    int t = threadIdx.x;
    sh[t] = (t < nb) ? bsum[t] : 0;
    __syncthreads();
    for (int off = 1; off < 256; off <<= 1) {
        int x = (t >= off) ? sh[t - off] : 0;
        __syncthreads();
        sh[t] += x;
        __syncthreads();
    }
    if (t < nb) bsum[t] = (t > 0) ? sh[t - 1] : 0;
}

// adds block offsets; also initializes cursor = rp (saves a d2d copy)
__global__ void k_scan3(int* __restrict__ rp, const int* __restrict__ bsum,
                        int* __restrict__ cursor, int n) {
    int i = blockIdx.x * blockDim.x + threadIdx.x;
    if (i < n) {
        int v = rp[i] + bsum[i >> 10];
        rp[i] = v;
        cursor[i] = v;
    }
    if (i == 0) rp[n] = NE;
}

// ---------------- fill CSR buckets: ep[pos] = (src, norm) ----------------
__global__ void k_fill(const int* __restrict__ src, const int* __restrict__ dst,
                       const float* __restrict__ ew, const float* __restrict__ dinv,
                       int* __restrict__ cursor, uint2* __restrict__ ep, int E) {
    int e = blockIdx.x * blockDim.x + threadIdx.x;
    if (e < E) {
        int s = src[e], d = dst[e];
        int pos = atomicAdd(&cursor[d], 1);
        float nv = dinv[s] * ew[e] * dinv[d];
        ep[pos] = make_uint2((uint32)s, __float_as_uint(nv));
    }
}

// ---------------- W prep: Wt[col][k] = bf16(W[k][col]) ----------------
__global__ void k_prepW(const float* __restrict__ W, ushort* __restrict__ Wt,
                        int K, int NOUT) {
    int o = blockIdx.x * blockDim.x + threadIdx.x;
    if (o < NOUT * K) {
        int col = o / K, k = o - col * K;
        Wt[o] = f2bf(W[(size_t)k * NOUT + col]);
    }
}

// ---------------- MFMA GEMM: H(bf16) = X(f32->bf16) @ W ----------------
// Block: 256 thr (4 waves), 64 rows x NOUT cols. K=128 fully staged, 1 barrier.
// LDS XOR-swizzle: 16B-block index ^= (row&7)  => 2-way conflicts (free).
template <int NOUT>
__global__ __launch_bounds__(256) void k_gemm_mfma(const float* __restrict__ X,
                                                   const ushort* __restrict__ Wt,
                                                   ushort* __restrict__ H, int N) {
    __shared__ char smem[64 * 256 + NOUT * 256];
    char* xs = smem;              // [64 rows][128 k] bf16, swizzled
    char* wt = smem + 64 * 256;   // [NOUT cols][128 k] bf16, swizzled
    const int tid = threadIdx.x;
    const int row0 = blockIdx.x * 64;

    // stage Wt (whole matrix, col-major rows of 256B)
    const uint4* Wt4 = reinterpret_cast<const uint4*>(Wt);
#pragma unroll
    for (int i = 0; i < NOUT / 16; ++i) {
        int id = tid + 256 * i;
        int col = id >> 4, c4 = id & 15;
        uint4 v = Wt4[id];
        *reinterpret_cast<uint4*>(wt + col * 256 + ((c4 * 16) ^ ((col & 7) << 4))) = v;
    }
    // stage X tile: 64 rows x 32 float4 chunks, convert to bf16
#pragma unroll
    for (int i = 0; i < 8; ++i) {
        int id = tid + 256 * i;
        int r = id >> 5, c4 = id & 31;
        int gr = row0 + r;
        float4 v = make_float4(0.f, 0.f, 0.f, 0.f);
        if (gr < N) v = *reinterpret_cast<const float4*>(&X[(size_t)gr * 128 + c4 * 4]);
        uint2 pk;
        pk.x = (uint32)f2bf(v.x) | ((uint32)f2bf(v.y) << 16);
        pk.y = (uint32)f2bf(v.z) | ((uint32)f2bf(v.w) << 16);
        *reinterpret_cast<uint2*>(xs + r * 256 + ((c4 * 8) ^ ((r & 7) << 4))) = pk;
    }
    __syncthreads();

    const int w = tid >> 6, lane = tid & 63;
    const int rl = w * 16 + (lane & 15);   // A row (local)
    const int kg = lane >> 4;              // k-group 0..3
    f32x4 acc[NOUT / 16];
#pragma unroll
    for (int ct = 0; ct < NOUT / 16; ++ct) acc[ct] = (f32x4){0.f, 0.f, 0.f, 0.f};

#pragma unroll
    for (int ks = 0; ks < 4; ++ks) {
        const int kb = ks * 64 + kg * 16;  // byte offset of this lane's 8 bf16 along k
        short8 a = *reinterpret_cast<const short8*>(xs + rl * 256 + (kb ^ ((rl & 7) << 4)));
#pragma unroll
        for (int ct = 0; ct < NOUT / 16; ++ct) {
            int col = ct * 16 + (lane & 15);
            short8 bfr = *reinterpret_cast<const short8*>(wt + col * 256 + (kb ^ ((col & 7) << 4)));
            acc[ct] = __builtin_amdgcn_mfma_f32_16x16x32_bf16(a, bfr, acc[ct], 0, 0, 0);
        }
    }
    // epilogue: C/D layout col=lane&15, row=(lane>>4)*4+reg (m89-verified)
#pragma unroll
    for (int ct = 0; ct < NOUT / 16; ++ct) {
        int col = ct * 16 + (lane & 15);
#pragma unroll
        for (int r = 0; r < 4; ++r) {
            int gr = row0 + w * 16 + (lane >> 4) * 4 + r;
            if (gr < N) H[(size_t)gr * NOUT + col] = f2bf(acc[ct][r]);
        }
    }
}

// ---------------- aggregate (D=128): 4 edge-slots x 16 lanes ----------------
template <int WAVES, int RELU>
__global__ void k_agg128(const int* __restrict__ rp, const uint2* __restrict__ ep,
                         const ushort* __restrict__ H, const float* __restrict__ b,
                         float* __restrict__ out, int N) {
    const int wave = threadIdx.x >> 6;
    const int lane = threadIdx.x & 63;
    const int n = blockIdx.x * WAVES + wave;
    if (n >= N) return;
    const int e0 = rp[n], e1 = rp[n + 1];
    const int slot = lane >> 4;   // 0..3
    const int l16 = lane & 15;    // feature chunk: feats l16*8 .. +7

    float a[8] = {};
    for (int e = e0 + slot; e < e1; e += 4) {
        uint2 p = ep[e];
        int s = (int)p.x;
        float w = __uint_as_float(p.y);
        uint4 hv = *reinterpret_cast<const uint4*>(&H[(size_t)s * 128 + l16 * 8]);
        a[0] = fmaf(w, bf2f(hv.x & 0xffffu), a[0]);
        a[1] = fmaf(w, bf2f(hv.x >> 16), a[1]);
        a[2] = fmaf(w, bf2f(hv.y & 0xffffu), a[2]);
        a[3] = fmaf(w, bf2f(hv.y >> 16), a[3]);
        a[4] = fmaf(w, bf2f(hv.z & 0xffffu), a[4]);
        a[5] = fmaf(w, bf2f(hv.z >> 16), a[5]);
        a[6] = fmaf(w, bf2f(hv.w & 0xffffu), a[6]);
        a[7] = fmaf(w, bf2f(hv.w >> 16), a[7]);
    }
#pragma unroll
    for (int j = 0; j < 8; ++j) {
        a[j] += __shfl_xor(a[j], 32);
        a[j] += __shfl_xor(a[j], 16);
    }
    if (lane < 16) {
        const float4 b0 = *reinterpret_cast<const float4*>(&b[l16 * 8]);
        const float4 b1 = *reinterpret_cast<const float4*>(&b[l16 * 8 + 4]);
        float4 o0 = make_float4(a[0] + b0.x, a[1] + b0.y, a[2] + b0.z, a[3] + b0.w);
        float4 o1 = make_float4(a[4] + b1.x, a[5] + b1.y, a[6] + b1.z, a[7] + b1.w);
        if (RELU) {
            o0.x = fmaxf(o0.x, 0.f); o0.y = fmaxf(o0.y, 0.f);
            o0.z = fmaxf(o0.z, 0.f); o0.w = fmaxf(o0.w, 0.f);
            o1.x = fmaxf(o1.x, 0.f); o1.y = fmaxf(o1.y, 0.f);
            o1.z = fmaxf(o1.z, 0.f); o1.w = fmaxf(o1.w, 0.f);
        }
        float* op = &out[(size_t)n * 128 + l16 * 8];
        *reinterpret_cast<float4*>(op) = o0;
        *reinterpret_cast<float4*>(op + 4) = o1;
    }
}

// ---------------- aggregate (D=64): 8 edge-slots x 8 lanes ----------------
template <int WAVES, int RELU>
__global__ void k_agg64(const int* __restrict__ rp, const uint2* __restrict__ ep,
                        const ushort* __restrict__ H, const float* __restrict__ b,
                        float* __restrict__ out, int N) {
    const int wave = threadIdx.x >> 6;
    const int lane = threadIdx.x & 63;
    const int n = blockIdx.x * WAVES + wave;
    if (n >= N) return;
    const int e0 = rp[n], e1 = rp[n + 1];
    const int slot = lane >> 3;   // 0..7
    const int l8 = lane & 7;      // feats l8*8 .. +7

    float a[8] = {};
    for (int e = e0 + slot; e < e1; e += 8) {
        uint2 p = ep[e];
        int s = (int)p.x;
        float w = __uint_as_float(p.y);
        uint4 hv = *reinterpret_cast<const uint4*>(&H[(size_t)s * 64 + l8 * 8]);
        a[0] = fmaf(w, bf2f(hv.x & 0xffffu), a[0]);
        a[1] = fmaf(w, bf2f(hv.x >> 16), a[1]);
        a[2] = fmaf(w, bf2f(hv.y & 0xffffu), a[2]);
        a[3] = fmaf(w, bf2f(hv.y >> 16), a[3]);
        a[4] = fmaf(w, bf2f(hv.z & 0xffffu), a[4]);
        a[5] = fmaf(w, bf2f(hv.z >> 16), a[5]);
        a[6] = fmaf(w, bf2f(hv.w & 0xffffu), a[6]);
        a[7] = fmaf(w, bf2f(hv.w >> 16), a[7]);
    }
#pragma unroll
    for (int j = 0; j < 8; ++j) {
        a[j] += __shfl_xor(a[j], 32);
        a[j] += __shfl_xor(a[j], 16);
        a[j] += __shfl_xor(a[j], 8);
    }
    if (lane < 8) {
        const float4 b0 = *reinterpret_cast<const float4*>(&b[l8 * 8]);
        const float4 b1 = *reinterpret_cast<const float4*>(&b[l8 * 8 + 4]);
        float4 o0 = make_float4(a[0] + b0.x, a[1] + b0.y, a[2] + b0.z, a[3] + b0.w);
        float4 o1 = make_float4(a[4] + b1.x, a[5] + b1.y, a[6] + b1.z, a[7] + b1.w);
        if (RELU) {
            o0.x = fmaxf(o0.x, 0.f); o0.y = fmaxf(o0.y, 0.f);
            o0.z = fmaxf(o0.z, 0.f); o0.w = fmaxf(o0.w, 0.f);
            o1.x = fmaxf(o1.x, 0.f); o1.y = fmaxf(o1.y, 0.f);
            o1.z = fmaxf(o1.z, 0.f); o1.w = fmaxf(o1.w, 0.f);
        }
        float* op = &out[(size_t)n * 64 + l8 * 8];
        *reinterpret_cast<float4*>(op) = o0;
        *reinterpret_cast<float4*>(op + 4) = o1;
    }
}

// ---------------- launch ----------------

extern "C" void kernel_launch(void* const* d_in, const int* in_sizes, int n_in,
                              void* d_out, int out_size, void* d_ws, size_t ws_size,
                              hipStream_t stream) {
    const float* x  = (const float*)d_in[0];
    const int*   ei = (const int*)d_in[1];
    const float* ew = (const float*)d_in[2];
    const float* W1 = (const float*)d_in[3];
    const float* b1 = (const float*)d_in[4];
    const float* W2 = (const float*)d_in[5];
    const float* b2 = (const float*)d_in[6];
    const float* W3 = (const float*)d_in[7];
    const float* b3 = (const float*)d_in[8];

    const int* src = ei;
    const int* dst = ei + NE;

    // ws layout
    float*  ws    = (float*)d_ws;
    float*  deg   = ws;                          // NN f (becomes dinv)
    int*    cnt   = (int*)(ws + NN);             // NN i (histogram -> cursor)
    int*    rp    = (int*)(ws + 2 * NN);         // NN+1 i
    int*    bsum  = (int*)(ws + 3 * NN + 64);    // 128 i
    uint2*  ep    = (uint2*)(ws + 3 * NN + 256); // NE uint2 (src, norm)
    ushort* h     = (ushort*)(ws + 3 * NN + 256 + 2 * NE); // NN*128 bf16
    ushort* wt1   = h + (size_t)NN * 128;        // 128*128 bf16 (W1^T)
    ushort* wt2   = wt1 + 128 * 128;             // 128*128 bf16
    ushort* wt3   = wt2 + 128 * 128;             // 64*128 bf16

    float* out0 = (float*)d_out;                 // [NN,128]
    float* out1 = out0 + NN * 128;               // [NN,128]
    float* out2 = out1 + NN * 128;               // [NN,64]

    const int B = 256;
    const int NB_SCAN = (NN + 1023) / 1024;      // 98

    // weight prep (independent)
    k_prepW<<<(128 * 128 + B - 1) / B, B, 0, stream>>>(W1, wt1, 128, 128);
    k_prepW<<<(128 * 128 + B - 1) / B, B, 0, stream>>>(W2, wt2, 128, 128);
    k_prepW<<<(128 * 64 + B - 1) / B, B, 0, stream>>>(W3, wt3, 128, 64);

    // CSR build (deg and cnt are adjacent -> one memset)
    hipMemsetAsync(deg, 0, 2 * NN * sizeof(float), stream);
    k_deg_hist<<<(NE + B - 1) / B, B, 0, stream>>>(dst, ew, deg, cnt, NE);
    k_dinv<<<(NN + B - 1) / B, B, 0, stream>>>(deg, NN);
    k_scan1<<<NB_SCAN, 256, 0, stream>>>(cnt, rp, bsum, NN);
    k_scan2<<<1, 256, 0, stream>>>(bsum, NB_SCAN);
    k_scan3<<<(NN + B - 1) / B, B, 0, stream>>>(rp, bsum, cnt, NN);
    k_fill<<<(NE + B - 1) / B, B, 0, stream>>>(src, dst, ew, deg, cnt, ep, NE);

    // ----- layer 1 -----
    k_gemm_mfma<128><<<(NN + 63) / 64, 256, 0, stream>>>(x, wt1, h, NN);
    k_agg128<4, 1><<<(NN + 3) / 4, 256, 0, stream>>>(rp, ep, h, b1, out0, NN);

    // ----- layer 2 -----
    k_gemm_mfma<128><<<(NN + 63) / 64, 256, 0, stream>>>(out0, wt2, h, NN);
    k_agg128<4, 1><<<(NN + 3) / 4, 256, 0, stream>>>(rp, ep, h, b2, out1, NN);

    // ----- layer 3 -----
    k_gemm_mfma<64><<<(NN + 63) / 64, 256, 0, stream>>>(out1, wt3, h, NN);
    k_agg64<4, 0><<<(NN + 3) / 4, 256, 0, stream>>>(rp, ep, h, b3, out2, NN);
}